// Round 2
// 492.342 us; speedup vs baseline: 1.0407x; 1.0407x over previous
//
#include <hip/hip_runtime.h>

typedef unsigned short ushort_t;
typedef __attribute__((ext_vector_type(8))) short short8;
typedef __attribute__((ext_vector_type(4))) float f32x4;
typedef __attribute__((ext_vector_type(8))) unsigned short us8;
typedef __attribute__((ext_vector_type(4))) unsigned short us4;

#define SEQ 2048
#define HIDD 2048
#define XLD 3072
#define SCALING 0.08838834764831843f

__device__ __forceinline__ float bf2f(ushort_t u) {
    unsigned int x = ((unsigned int)u) << 16;
    return __builtin_bit_cast(float, x);
}
__device__ __forceinline__ ushort_t f2bf(float f) {
    unsigned int u = __builtin_bit_cast(unsigned int, f);
    u += 0x7fffu + ((u >> 16) & 1u);
    return (ushort_t)(u >> 16);
}

// ------- Transpose + convert: W (K x N) f32 row-major -> Wt rows, bf16 -------
__device__ __forceinline__ void transpose_tile(
    const float* __restrict__ W, ushort_t* __restrict__ Wt,
    int N, int n0, int k0, int dstRow0) {
    __shared__ ushort_t t[64 * 80];
    const int tid = threadIdx.x;
    {
        const int kl = tid >> 4;          // 0..15
        const int nc = (tid & 15) * 4;    // 0..60
        #pragma unroll
        for (int p = 0; p < 4; ++p) {
            int k = kl + p * 16;
            float4 v = *(const float4*)(W + (size_t)(k0 + k) * N + n0 + nc);
            t[(nc + 0) * 80 + k] = f2bf(v.x);
            t[(nc + 1) * 80 + k] = f2bf(v.y);
            t[(nc + 2) * 80 + k] = f2bf(v.z);
            t[(nc + 3) * 80 + k] = f2bf(v.w);
        }
    }
    __syncthreads();
    {
        const int nl = tid >> 3;          // 0..31
        const int kc = (tid & 7) * 8;     // 0..56
        #pragma unroll
        for (int p = 0; p < 2; ++p) {
            int n = nl + p * 32;
            *(us8*)(Wt + (size_t)(dstRow0 + n) * HIDD + k0 + kc) =
                *(const us8*)&t[n * 80 + kc];
        }
    }
}

// All four weight transposes + the hidden f32->bf16 convert in ONE launch.
__global__ __launch_bounds__(256) void transpose_all(
    const float* __restrict__ Wq, const float* __restrict__ Wk,
    const float* __restrict__ Wv, const float* __restrict__ Wo,
    const float* __restrict__ hid,
    ushort_t* __restrict__ Wqkvt, ushort_t* __restrict__ Wot,
    ushort_t* __restrict__ Hb) {
    int bx = blockIdx.x, k0 = blockIdx.y * 64;
    if (bx < 32)       transpose_tile(Wq, Wqkvt, 2048, bx * 64,        k0, bx * 64);
    else if (bx < 40)  transpose_tile(Wk, Wqkvt, 512,  (bx - 32) * 64, k0, 2048 + (bx - 32) * 64);
    else if (bx < 48)  transpose_tile(Wv, Wqkvt, 512,  (bx - 40) * 64, k0, 2560 + (bx - 40) * 64);
    else if (bx < 80)  transpose_tile(Wo, Wot,   2048, (bx - 48) * 64, k0, (bx - 48) * 64);
    else {
        int chunk = (bx - 80) * 32 + blockIdx.y;   // 0..1023, 4096 floats each
        size_t base = (size_t)chunk * 4096 + threadIdx.x * 16;
        #pragma unroll
        for (int p = 0; p < 4; ++p) {
            float4 v = *(const float4*)(hid + base + p * 4);
            us4 o;
            o[0] = f2bf(v.x); o[1] = f2bf(v.y); o[2] = f2bf(v.z); o[3] = f2bf(v.w);
            *(us4*)(Hb + base + p * 4) = o;
        }
    }
}

// -------- GEMM split-K: P[z] (MxN bf16) = A(:, koff..) * Bt(:, koff..)^T -----
__global__ __launch_bounds__(256) void gemm_splitk(
    const ushort_t* __restrict__ A, int lda,
    const ushort_t* __restrict__ Bt, int ldb,
    ushort_t* __restrict__ P, int ldc,
    const int4 kexts) {
    __shared__ ushort_t lA[2 * 128 * 32];
    __shared__ ushort_t lB[2 * 128 * 32];
    const int tid = threadIdx.x;
    const int wave = tid >> 6, lane = tid & 63;
    const int wm = wave >> 1, wn = wave & 1;
    const int quad = lane >> 4, l16 = lane & 15;
    const int m0 = blockIdx.y * 128, n0 = blockIdx.x * 128;
    const int z = blockIdx.z;

    const int ke[4] = {kexts.x, kexts.y, kexts.z, kexts.w};
    int koff = 0;
    for (int zz = 0; zz < 4; ++zz) if (zz < z) koff += ke[zz];
    const int kext = ke[z];

    A  += (size_t)koff;
    Bt += (size_t)koff;
    P  += (size_t)z * ((size_t)gridDim.y * 128) * ldc;

    const int srow = lane >> 2;                      // 0..15
    const int scol = 8 * ((lane & 3) ^ (srow & 3));  // swizzled 16B col-block

    f32x4 acc[4][4] = {};

    const ushort_t* Ab = A  + (size_t)(m0 + wave * 16 + srow) * lda + scol;
    const ushort_t* Bb = Bt + (size_t)(n0 + wave * 16 + srow) * ldb + scol;
    ushort_t* lAw = lA + (wave * 16) * 32;
    ushort_t* lBw = lB + (wave * 16) * 32;

    const int rsw = (quad ^ (l16 & 3)) * 8;

    for (int kk = 0; kk < kext; kk += 64) {
        __syncthreads();
        #pragma unroll
        for (int kh = 0; kh < 2; ++kh) {
            #pragma unroll
            for (int c = 0; c < 2; ++c) {
                __builtin_amdgcn_global_load_lds(
                    (const __attribute__((address_space(1))) unsigned int*)(const void*)
                        (Ab + (size_t)(c * 64) * lda + kk + kh * 32),
                    (__attribute__((address_space(3))) unsigned int*)(void*)
                        (lAw + kh * 128 * 32 + c * 64 * 32), 16, 0, 0);
                __builtin_amdgcn_global_load_lds(
                    (const __attribute__((address_space(1))) unsigned int*)(const void*)
                        (Bb + (size_t)(c * 64) * ldb + kk + kh * 32),
                    (__attribute__((address_space(3))) unsigned int*)(void*)
                        (lBw + kh * 128 * 32 + c * 64 * 32), 16, 0, 0);
            }
        }
        __syncthreads();
        #pragma unroll
        for (int kh = 0; kh < 2; ++kh) {
            short8 af[4], bfr[4];
            #pragma unroll
            for (int mt = 0; mt < 4; ++mt)
                af[mt] = *(const short8*)&lA[kh * 128 * 32 + (wm * 64 + mt * 16 + l16) * 32 + rsw];
            #pragma unroll
            for (int nt = 0; nt < 4; ++nt)
                bfr[nt] = *(const short8*)&lB[kh * 128 * 32 + (wn * 64 + nt * 16 + l16) * 32 + rsw];
            #pragma unroll
            for (int mt = 0; mt < 4; ++mt) {
                #pragma unroll
                for (int nt = 0; nt < 4; ++nt)
                    acc[mt][nt] = __builtin_amdgcn_mfma_f32_16x16x32_bf16(
                        af[mt], bfr[nt], acc[mt][nt], 0, 0, 0);
            }
        }
    }

    #pragma unroll
    for (int mt = 0; mt < 4; ++mt) {
        #pragma unroll
        for (int nt = 0; nt < 4; ++nt) {
            int gm = m0 + wm * 64 + mt * 16 + quad * 4;
            int gn = n0 + wn * 64 + nt * 16 + l16;
            #pragma unroll
            for (int r = 0; r < 4; ++r)
                P[(size_t)(gm + r) * ldc + gn] = f2bf(acc[mt][nt][r]);
        }
    }
}

// ---- Fused split-K(2) reduce for X: RoPE path (Q/K cols) + V path -----------
// Vectorized: one wave per (row, 256-col span). RoPE pair (d, d+64) exchanged
// in-register via shfl_xor(16) instead of scalar 2-byte re-loads.
#define RWAVES (SEQ * 10)   /* RoPE region: cols 0..2559, 10 x 256-col spans */
#define VWAVES (SEQ * 2)    /* V region:    cols 2560..3071, 2 x 256-col spans */
__global__ __launch_bounds__(256) void reduce_x(
    const ushort_t* __restrict__ P, ushort_t* __restrict__ X,
    const float* __restrict__ cosp, const float* __restrict__ sinp) {
    const size_t ZS = (size_t)SEQ * XLD;
    int wid = blockIdx.x * 4 + (threadIdx.x >> 6);
    int lane = threadIdx.x & 63;
    if (wid < RWAVES) {
        int s = wid / 10, seg = wid % 10;
        int c0 = seg * 256 + lane * 4;          // 4 contiguous cols per lane
        size_t base = (size_t)s * XLD + c0;
        us4 a = *(const us4*)(P + base);
        us4 b = *(const us4*)(P + ZS + base);
        float x[4];
        #pragma unroll
        for (int t = 0; t < 4; ++t) x[t] = bf2f(a[t]) + bf2f(b[t]);
        float p[4];
        #pragma unroll
        for (int t = 0; t < 4; ++t) p[t] = __shfl_xor(x[t], 16, 64);
        int d = (lane * 4) & 127;               // within-head col
        float4 cv = *(const float4*)(cosp + (size_t)s * 128 + d);
        float4 sv = *(const float4*)(sinp + (size_t)s * 128 + d);
        float sgn = (lane & 16) ? 1.f : -1.f;   // hi half: +x1*sin, lo: -x2*sin
        us4 o;
        o[0] = f2bf(x[0] * cv.x + sgn * p[0] * sv.x);
        o[1] = f2bf(x[1] * cv.y + sgn * p[1] * sv.y);
        o[2] = f2bf(x[2] * cv.z + sgn * p[2] * sv.z);
        o[3] = f2bf(x[3] * cv.w + sgn * p[3] * sv.w);
        *(us4*)(X + base) = o;
    } else {
        int w2 = wid - RWAVES;                  // 0..VWAVES-1
        int s = w2 >> 1;
        int c0 = 2560 + (w2 & 1) * 256 + lane * 4;
        size_t base = (size_t)s * XLD + c0;
        us4 a = *(const us4*)(P + base);
        us4 b = *(const us4*)(P + ZS + base);
        us4 o;
        #pragma unroll
        for (int t = 0; t < 4; ++t) o[t] = f2bf(bf2f(a[t]) + bf2f(b[t]));
        *(us4*)(X + base) = o;
    }
}

// ---- Split-K(3) reduce for the final output (bf16 partials -> f32 out) ------
__global__ __launch_bounds__(256) void reduce_out3(
    const ushort_t* __restrict__ P, float* __restrict__ out) {
    const size_t ZS = (size_t)SEQ * HIDD;
    size_t idx = ((size_t)blockIdx.x * 256 + threadIdx.x) * 4;
    us4 a = *(const us4*)(P + idx);
    us4 b = *(const us4*)(P + ZS + idx);
    us4 c = *(const us4*)(P + 2 * ZS + idx);
    float4 o;
    o.x = bf2f(a[0]) + bf2f(b[0]) + bf2f(c[0]);
    o.y = bf2f(a[1]) + bf2f(b[1]) + bf2f(c[1]);
    o.z = bf2f(a[2]) + bf2f(b[2]) + bf2f(c[2]);
    o.w = bf2f(a[3]) + bf2f(b[3]) + bf2f(c[3]);
    *(float4*)(out + idx) = o;
}

// ---------------- Attention: one wave per (head h, query i) ------------------
// Wave-parallel QK: 3 rounds of {16 j-slots x 4-lane groups x 32 dims}.
// Each lane vector-loads its 64B K-segment; reduce is 2 shfl_xor per round
// (vs 6 shfl per j serially = ~222 dependent LDS ops before).
__device__ __forceinline__ float qk_round(
    const ushort_t* __restrict__ Kbase, const float* qf,
    int jg, int dg, int lo, int nsink, int r) {
    int jj = r * 16 + jg;
    int j = (jj < nsink) ? jj : (lo + jj - nsink);
    if (j > SEQ - 1) j = SEQ - 1;               // clamp OOB slots (masked later)
    const uint4* kp = (const uint4*)(Kbase + (size_t)j * XLD + dg * 32);
    float p = 0.f;
    #pragma unroll
    for (int pq = 0; pq < 4; ++pq) {
        uint4 v = kp[pq];
        unsigned int uu[4] = {v.x, v.y, v.z, v.w};
        #pragma unroll
        for (int t = 0; t < 4; ++t) {
            p += qf[pq * 8 + t * 2]     * bf2f((ushort_t)(uu[t] & 0xffffu));
            p += qf[pq * 8 + t * 2 + 1] * bf2f((ushort_t)(uu[t] >> 16));
        }
    }
    p += __shfl_xor(p, 1, 64);
    p += __shfl_xor(p, 2, 64);
    return p * SCALING;
}

__global__ __launch_bounds__(256) void attn_kernel(
    const ushort_t* __restrict__ X, float* __restrict__ Wts,
    ushort_t* __restrict__ Aout) {
    int g = blockIdx.x * 4 + (threadIdx.x >> 6);
    int lane = threadIdx.x & 63;
    int i = g & (SEQ - 1);
    int h = g >> 11;

    const int dg = lane & 3;      // 32-dim segment owner within 4-lane group
    const int jg = lane >> 2;     // j-slot group 0..15

    const ushort_t* Q = X + (size_t)i * XLD + h * 128;
    // This lane's 32-dim quarter of Q, unpacked to f32 registers.
    float qf[32];
    {
        const uint4* qp = (const uint4*)(Q + dg * 32);
        #pragma unroll
        for (int p = 0; p < 4; ++p) {
            uint4 v = qp[p];
            unsigned int uu[4] = {v.x, v.y, v.z, v.w};
            #pragma unroll
            for (int t = 0; t < 4; ++t) {
                qf[p * 8 + t * 2]     = bf2f((ushort_t)(uu[t] & 0xffffu));
                qf[p * 8 + t * 2 + 1] = bf2f((ushort_t)(uu[t] >> 16));
            }
        }
    }

    int lo = i - 32; if (lo < 0) lo = 0;
    int nsink = lo < 4 ? lo : 4;
    int NJ = nsink + (i - lo + 1);              // <= 37

    const ushort_t* Kbase = X + 2048 + (h >> 2) * 128;
    const ushort_t* Vbase = X + 2560 + (h >> 2) * 128;

    float s0 = qk_round(Kbase, qf, jg, dg, lo, nsink, 0);
    float s1 = qk_round(Kbase, qf, jg, dg, lo, nsink, 1);
    float s2 = qk_round(Kbase, qf, jg, dg, lo, nsink, 2);

    // gather: lane l takes score of slot l (round l>>4, group l&15, src dg=0)
    int src = (lane & 15) * 4;
    float m0 = __shfl(s0, src, 64);
    float m1 = __shfl(s1, src, 64);
    float m2 = __shfl(s2, src, 64);
    float mysc = (lane < 16) ? m0 : ((lane < 32) ? m1 : m2);
    if (lane >= NJ) mysc = -1e30f;

    float m = mysc;
    #pragma unroll
    for (int off = 32; off > 0; off >>= 1) m = fmaxf(m, __shfl_xor(m, off, 64));

    float e = (lane < NJ) ? expf(mysc - m) : 0.f;
    float l = e;
    #pragma unroll
    for (int off = 32; off > 0; off >>= 1) l += __shfl_xor(l, off, 64);
    float w = e / l;   // lane jj holds weight for slot jj (jj < NJ)

    // dense weights row: 2048 f32 = 8 slots x (64 lanes x float4)
    float* row = Wts + ((size_t)h * SEQ + i) * SEQ;
    #pragma unroll
    for (int s = 0; s < 8; ++s) {
        float4 o;
        #pragma unroll
        for (int t = 0; t < 4; ++t) {
            int c = s * 256 + lane * 4 + t;
            bool in = (c < nsink) || (c >= lo && c <= i);
            int jjc = in ? ((c < nsink) ? c : (nsink + c - lo)) : 0;
            float wv = __shfl(w, jjc, 64);
            o[t] = in ? wv : 0.f;
        }
        *(float4*)(row + s * 256 + lane * 4) = o;
    }

    float o0 = 0.f, o1 = 0.f;
    for (int jj = 0; jj < NJ; ++jj) {
        int j = (jj < nsink) ? jj : (lo + jj - nsink);
        float pb = __shfl(w, jj, 64);
        unsigned int vv = *(const unsigned int*)(Vbase + (size_t)j * XLD + 2 * lane);
        o0 += pb * bf2f((ushort_t)(vv & 0xffff));
        o1 += pb * bf2f((ushort_t)(vv >> 16));
    }
    int r = h * 128 + (i >> 4);
    int c = (i & 15) * 128 + 2 * lane;
    ushort_t* Ar = Aout + (size_t)r * HIDD + c;
    Ar[0] = f2bf(o0);
    Ar[1] = f2bf(o1);
}

extern "C" void kernel_launch(void* const* d_in, const int* in_sizes, int n_in,
                              void* d_out, int out_size, void* d_ws, size_t ws_size,
                              hipStream_t stream) {
    if (n_in < 7) return;
    const float* hid  = (const float*)d_in[0];
    const float* cosp = (const float*)d_in[1];
    const float* sinp = (const float*)d_in[2];
    const float* Wq   = (const float*)d_in[3];
    const float* Wk   = (const float*)d_in[4];
    const float* Wv   = (const float*)d_in[5];
    const float* Wo   = (const float*)d_in[6];

    float* out = (float*)d_out;                  // attn_output (f32)
    float* wts = out + (size_t)SEQ * HIDD;       // attn_weights (f32)

    // workspace layout (all bf16 elems)
    ushort_t* Hb    = (ushort_t*)d_ws;                    // 2048x2048
    ushort_t* Wqkvt = Hb    + (size_t)2048 * 2048;        // 3072x2048
    ushort_t* Wot   = Wqkvt + (size_t)3072 * 2048;        // 2048x2048
    ushort_t* X     = Wot   + (size_t)2048 * 2048;        // 2048x3072
    ushort_t* Am    = X     + (size_t)SEQ * XLD;          // 2048x2048
    ushort_t* Pqkv  = Am    + (size_t)SEQ * HIDD;         // 2 x 2048x3072
    ushort_t* Pout  = Pqkv  + 2 * (size_t)SEQ * XLD;      // 3 x 2048x2048
    size_t need = ((char*)(Pout + 3 * (size_t)SEQ * HIDD)) - (char*)d_ws;
    if (ws_size < need) return;

    dim3 blk(256);
    // all weight transposes + hidden convert in one launch
    transpose_all<<<dim3(112, 32), blk, 0, stream>>>(
        Wq, Wk, Wv, Wo, hid, Wqkvt, Wot, Hb);

    // fused QKV projection, split-K=2 (1024+1024) -> bf16 partials
    gemm_splitk<<<dim3(24, 16, 2), blk, 0, stream>>>(
        Hb, HIDD, Wqkvt, 2048, Pqkv, XLD, make_int4(1024, 1024, 0, 0));
    reduce_x<<<(RWAVES + VWAVES) / 4, blk, 0, stream>>>(
        Pqkv, X, cosp, sinp);

    // attention: dense weights rows (no memset) + Am
    attn_kernel<<<(SEQ * 16) / 4, blk, 0, stream>>>(X, wts, Am);

    // output projection, split-K=3 (704+704+640, all x64, full residency)
    gemm_splitk<<<dim3(16, 16, 3), blk, 0, stream>>>(
        Am, HIDD, Wot, 2048, Pout, HIDD, make_int4(704, 704, 640, 0));
    reduce_out3<<<(SEQ * HIDD) / (256 * 4), blk, 0, stream>>>(Pout, out);
}

// Round 3
// 447.606 us; speedup vs baseline: 1.1447x; 1.0999x over previous
//
#include <hip/hip_runtime.h>

typedef unsigned short ushort_t;
typedef __attribute__((ext_vector_type(8))) short short8;
typedef __attribute__((ext_vector_type(4))) float f32x4;
typedef __attribute__((ext_vector_type(8))) unsigned short us8;
typedef __attribute__((ext_vector_type(4))) unsigned short us4;

#define SEQ 2048
#define HIDD 2048
#define XLD 3072
#define SCALING 0.08838834764831843f

__device__ __forceinline__ float bf2f(ushort_t u) {
    unsigned int x = ((unsigned int)u) << 16;
    return __builtin_bit_cast(float, x);
}
__device__ __forceinline__ ushort_t f2bf(float f) {
    unsigned int u = __builtin_bit_cast(unsigned int, f);
    u += 0x7fffu + ((u >> 16) & 1u);
    return (ushort_t)(u >> 16);
}

// ------- Transpose + convert: W (K x N) f32 row-major -> Wt rows, bf16 -------
__device__ __forceinline__ void transpose_tile(
    const float* __restrict__ W, ushort_t* __restrict__ Wt,
    int N, int n0, int k0, int dstRow0) {
    __shared__ ushort_t t[64 * 80];
    const int tid = threadIdx.x;
    {
        const int kl = tid >> 4;          // 0..15
        const int nc = (tid & 15) * 4;    // 0..60
        #pragma unroll
        for (int p = 0; p < 4; ++p) {
            int k = kl + p * 16;
            float4 v = *(const float4*)(W + (size_t)(k0 + k) * N + n0 + nc);
            t[(nc + 0) * 80 + k] = f2bf(v.x);
            t[(nc + 1) * 80 + k] = f2bf(v.y);
            t[(nc + 2) * 80 + k] = f2bf(v.z);
            t[(nc + 3) * 80 + k] = f2bf(v.w);
        }
    }
    __syncthreads();
    {
        const int nl = tid >> 3;          // 0..31
        const int kc = (tid & 7) * 8;     // 0..56
        #pragma unroll
        for (int p = 0; p < 2; ++p) {
            int n = nl + p * 32;
            *(us8*)(Wt + (size_t)(dstRow0 + n) * HIDD + k0 + kc) =
                *(const us8*)&t[n * 80 + kc];
        }
    }
}

// All four weight transposes + the hidden f32->bf16 convert in ONE launch.
__global__ __launch_bounds__(256) void transpose_all(
    const float* __restrict__ Wq, const float* __restrict__ Wk,
    const float* __restrict__ Wv, const float* __restrict__ Wo,
    const float* __restrict__ hid,
    ushort_t* __restrict__ Wqkvt, ushort_t* __restrict__ Wot,
    ushort_t* __restrict__ Hb) {
    int bx = blockIdx.x, k0 = blockIdx.y * 64;
    if (bx < 32)       transpose_tile(Wq, Wqkvt, 2048, bx * 64,        k0, bx * 64);
    else if (bx < 40)  transpose_tile(Wk, Wqkvt, 512,  (bx - 32) * 64, k0, 2048 + (bx - 32) * 64);
    else if (bx < 48)  transpose_tile(Wv, Wqkvt, 512,  (bx - 40) * 64, k0, 2560 + (bx - 40) * 64);
    else if (bx < 80)  transpose_tile(Wo, Wot,   2048, (bx - 48) * 64, k0, (bx - 48) * 64);
    else {
        int chunk = (bx - 80) * 32 + blockIdx.y;   // 0..1023, 4096 floats each
        size_t base = (size_t)chunk * 4096 + threadIdx.x * 16;
        #pragma unroll
        for (int p = 0; p < 4; ++p) {
            float4 v = *(const float4*)(hid + base + p * 4);
            us4 o;
            o[0] = f2bf(v.x); o[1] = f2bf(v.y); o[2] = f2bf(v.z); o[3] = f2bf(v.w);
            *(us4*)(Hb + base + p * 4) = o;
        }
    }
}

// -------- GEMM split-K: P[z] (MxN bf16) = A(:, koff..) * Bt(:, koff..)^T -----
__global__ __launch_bounds__(256) void gemm_splitk(
    const ushort_t* __restrict__ A, int lda,
    const ushort_t* __restrict__ Bt, int ldb,
    ushort_t* __restrict__ P, int ldc,
    const int4 kexts) {
    __shared__ ushort_t lA[2 * 128 * 32];
    __shared__ ushort_t lB[2 * 128 * 32];
    const int tid = threadIdx.x;
    const int wave = tid >> 6, lane = tid & 63;
    const int wm = wave >> 1, wn = wave & 1;
    const int quad = lane >> 4, l16 = lane & 15;
    const int m0 = blockIdx.y * 128, n0 = blockIdx.x * 128;
    const int z = blockIdx.z;

    const int ke[4] = {kexts.x, kexts.y, kexts.z, kexts.w};
    int koff = 0;
    for (int zz = 0; zz < 4; ++zz) if (zz < z) koff += ke[zz];
    const int kext = ke[z];

    A  += (size_t)koff;
    Bt += (size_t)koff;
    P  += (size_t)z * ((size_t)gridDim.y * 128) * ldc;

    const int srow = lane >> 2;                      // 0..15
    const int scol = 8 * ((lane & 3) ^ (srow & 3));  // swizzled 16B col-block

    f32x4 acc[4][4] = {};

    const ushort_t* Ab = A  + (size_t)(m0 + wave * 16 + srow) * lda + scol;
    const ushort_t* Bb = Bt + (size_t)(n0 + wave * 16 + srow) * ldb + scol;
    ushort_t* lAw = lA + (wave * 16) * 32;
    ushort_t* lBw = lB + (wave * 16) * 32;

    const int rsw = (quad ^ (l16 & 3)) * 8;

    for (int kk = 0; kk < kext; kk += 64) {
        __syncthreads();
        #pragma unroll
        for (int kh = 0; kh < 2; ++kh) {
            #pragma unroll
            for (int c = 0; c < 2; ++c) {
                __builtin_amdgcn_global_load_lds(
                    (const __attribute__((address_space(1))) unsigned int*)(const void*)
                        (Ab + (size_t)(c * 64) * lda + kk + kh * 32),
                    (__attribute__((address_space(3))) unsigned int*)(void*)
                        (lAw + kh * 128 * 32 + c * 64 * 32), 16, 0, 0);
                __builtin_amdgcn_global_load_lds(
                    (const __attribute__((address_space(1))) unsigned int*)(const void*)
                        (Bb + (size_t)(c * 64) * ldb + kk + kh * 32),
                    (__attribute__((address_space(3))) unsigned int*)(void*)
                        (lBw + kh * 128 * 32 + c * 64 * 32), 16, 0, 0);
            }
        }
        __syncthreads();
        #pragma unroll
        for (int kh = 0; kh < 2; ++kh) {
            short8 af[4], bfr[4];
            #pragma unroll
            for (int mt = 0; mt < 4; ++mt)
                af[mt] = *(const short8*)&lA[kh * 128 * 32 + (wm * 64 + mt * 16 + l16) * 32 + rsw];
            #pragma unroll
            for (int nt = 0; nt < 4; ++nt)
                bfr[nt] = *(const short8*)&lB[kh * 128 * 32 + (wn * 64 + nt * 16 + l16) * 32 + rsw];
            #pragma unroll
            for (int mt = 0; mt < 4; ++mt) {
                #pragma unroll
                for (int nt = 0; nt < 4; ++nt)
                    acc[mt][nt] = __builtin_amdgcn_mfma_f32_16x16x32_bf16(
                        af[mt], bfr[nt], acc[mt][nt], 0, 0, 0);
            }
        }
    }

    #pragma unroll
    for (int mt = 0; mt < 4; ++mt) {
        #pragma unroll
        for (int nt = 0; nt < 4; ++nt) {
            int gm = m0 + wm * 64 + mt * 16 + quad * 4;
            int gn = n0 + wn * 64 + nt * 16 + l16;
            #pragma unroll
            for (int r = 0; r < 4; ++r)
                P[(size_t)(gm + r) * ldc + gn] = f2bf(acc[mt][nt][r]);
        }
    }
}

// ---- Fused split-K(2) reduce for X: RoPE path (Q/K cols) + V path -----------
#define RWAVES (SEQ * 10)   /* RoPE region: cols 0..2559, 10 x 256-col spans */
#define VWAVES (SEQ * 2)    /* V region:    cols 2560..3071, 2 x 256-col spans */
__global__ __launch_bounds__(256) void reduce_x(
    const ushort_t* __restrict__ P, ushort_t* __restrict__ X,
    const float* __restrict__ cosp, const float* __restrict__ sinp) {
    const size_t ZS = (size_t)SEQ * XLD;
    int wid = blockIdx.x * 4 + (threadIdx.x >> 6);
    int lane = threadIdx.x & 63;
    if (wid < RWAVES) {
        int s = wid / 10, seg = wid % 10;
        int c0 = seg * 256 + lane * 4;          // 4 contiguous cols per lane
        size_t base = (size_t)s * XLD + c0;
        us4 a = *(const us4*)(P + base);
        us4 b = *(const us4*)(P + ZS + base);
        float x[4];
        #pragma unroll
        for (int t = 0; t < 4; ++t) x[t] = bf2f(a[t]) + bf2f(b[t]);
        float p[4];
        #pragma unroll
        for (int t = 0; t < 4; ++t) p[t] = __shfl_xor(x[t], 16, 64);
        int d = (lane * 4) & 127;               // within-head col
        float4 cv = *(const float4*)(cosp + (size_t)s * 128 + d);
        float4 sv = *(const float4*)(sinp + (size_t)s * 128 + d);
        float sgn = (lane & 16) ? 1.f : -1.f;   // hi half: +x1*sin, lo: -x2*sin
        us4 o;
        o[0] = f2bf(x[0] * cv.x + sgn * p[0] * sv.x);
        o[1] = f2bf(x[1] * cv.y + sgn * p[1] * sv.y);
        o[2] = f2bf(x[2] * cv.z + sgn * p[2] * sv.z);
        o[3] = f2bf(x[3] * cv.w + sgn * p[3] * sv.w);
        *(us4*)(X + base) = o;
    } else {
        int w2 = wid - RWAVES;                  // 0..VWAVES-1
        int s = w2 >> 1;
        int c0 = 2560 + (w2 & 1) * 256 + lane * 4;
        size_t base = (size_t)s * XLD + c0;
        us4 a = *(const us4*)(P + base);
        us4 b = *(const us4*)(P + ZS + base);
        us4 o;
        #pragma unroll
        for (int t = 0; t < 4; ++t) o[t] = f2bf(bf2f(a[t]) + bf2f(b[t]));
        *(us4*)(X + base) = o;
    }
}

// ---- Split-K(3) reduce for the final output (bf16 partials -> f32 out) ------
__global__ __launch_bounds__(256) void reduce_out3(
    const ushort_t* __restrict__ P, float* __restrict__ out) {
    const size_t ZS = (size_t)SEQ * HIDD;
    size_t idx = ((size_t)blockIdx.x * 256 + threadIdx.x) * 4;
    us4 a = *(const us4*)(P + idx);
    us4 b = *(const us4*)(P + ZS + idx);
    us4 c = *(const us4*)(P + 2 * ZS + idx);
    float4 o;
    o.x = bf2f(a[0]) + bf2f(b[0]) + bf2f(c[0]);
    o.y = bf2f(a[1]) + bf2f(b[1]) + bf2f(c[1]);
    o.z = bf2f(a[2]) + bf2f(b[2]) + bf2f(c[2]);
    o.w = bf2f(a[3]) + bf2f(b[3]) + bf2f(c[3]);
    *(float4*)(out + idx) = o;
}

// ---------------- Attention: one block per (head h, 16 queries) --------------
// The 16 queries i0..i0+15 share a 48-row K/V window [w0, w0+47] plus sink
// rows 0..3. Stage all 104 rows (52 K + 52 V) in LDS once (row stride 136
// ushorts = 272 B = 17 x 16 B -> consecutive rows land on distinct 16 B
// bank-slots, so the 16-row qk read is 2-way = free). Then each of the 4
// waves processes 4 queries entirely from LDS.
// LDS rows: 0..47 = K window (w0+r), 48..51 = K sinks 0..3,
//           52..99 = V window,       100..103 = V sinks.
#define SMLD 136
__device__ __forceinline__ float qk_round_lds(
    const ushort_t* __restrict__ sm, const float* qf,
    int jg, int dg, int lo, int nsink, int w0, int r) {
    int jj = r * 16 + jg;
    int row;
    if (jj < nsink) row = 48 + jj;
    else {
        int widx = lo + jj - nsink - w0;
        if (widx > 47) widx = 47;           // OOB slots clamped (masked later)
        row = widx;
    }
    const ushort_t* kp = sm + row * SMLD + dg * 32;
    float p = 0.f;
    #pragma unroll
    for (int pq = 0; pq < 4; ++pq) {
        us8 v = *(const us8*)(kp + pq * 8);
        #pragma unroll
        for (int t = 0; t < 8; ++t) p += qf[pq * 8 + t] * bf2f(v[t]);
    }
    p += __shfl_xor(p, 1, 64);
    p += __shfl_xor(p, 2, 64);
    return p * SCALING;
}

__global__ __launch_bounds__(256) void attn_kernel(
    const ushort_t* __restrict__ X, float* __restrict__ Wts,
    ushort_t* __restrict__ Aout) {
    __shared__ ushort_t sm[104 * SMLD];
    const int tid = threadIdx.x;
    const int lane = tid & 63;
    const int wv = tid >> 6;
    const int h = blockIdx.x >> 7;
    const int i0 = (blockIdx.x & 127) << 4;
    const int w0 = (i0 >= 32) ? (i0 - 32) : 0;
    const int kvh = h >> 2;

    const ushort_t* Kg = X + 2048 + kvh * 128;
    const ushort_t* Vg = X + 2560 + kvh * 128;

    // stage: 104 row-tasks, 16 threads x 16 B each
    #pragma unroll
    for (int p = 0; p < 7; ++p) {
        int tau = p * 16 + (tid >> 4);
        if (tau < 104) {
            int rr = (tau < 52) ? tau : (tau - 52);
            int grow = (rr < 48) ? (w0 + rr) : (rr - 48);
            const ushort_t* src = ((tau < 52) ? Kg : Vg) + (size_t)grow * XLD + (tid & 15) * 8;
            *(us8*)&sm[tau * SMLD + (tid & 15) * 8] = *(const us8*)src;
        }
    }
    __syncthreads();

    const int dg = lane & 3;      // 32-dim segment owner within 4-lane group
    const int jg = lane >> 2;     // j-slot group 0..15

    for (int ii = 0; ii < 4; ++ii) {
        const int i = i0 + wv * 4 + ii;

        // this lane's 32-dim quarter of Q, unpacked to f32
        float qf[32];
        {
            const ushort_t* Q = X + (size_t)i * XLD + h * 128 + dg * 32;
            #pragma unroll
            for (int pq = 0; pq < 4; ++pq) {
                us8 v = *(const us8*)(Q + pq * 8);
                #pragma unroll
                for (int t = 0; t < 8; ++t) qf[pq * 8 + t] = bf2f(v[t]);
            }
        }

        int lo = i - 32; if (lo < 0) lo = 0;
        int nsink = lo < 4 ? lo : 4;
        int NJ = nsink + (i - lo + 1);          // <= 37

        float s0 = qk_round_lds(sm, qf, jg, dg, lo, nsink, w0, 0);
        float s1 = qk_round_lds(sm, qf, jg, dg, lo, nsink, w0, 1);
        float s2 = qk_round_lds(sm, qf, jg, dg, lo, nsink, w0, 2);

        // gather: lane l takes score of slot l (round l>>4, group l&15, dg=0)
        int src = (lane & 15) * 4;
        float m0 = __shfl(s0, src, 64);
        float m1 = __shfl(s1, src, 64);
        float m2 = __shfl(s2, src, 64);
        float mysc = (lane < 16) ? m0 : ((lane < 32) ? m1 : m2);
        if (lane >= NJ) mysc = -1e30f;

        float m = mysc;
        #pragma unroll
        for (int off = 32; off > 0; off >>= 1) m = fmaxf(m, __shfl_xor(m, off, 64));

        float e = (lane < NJ) ? expf(mysc - m) : 0.f;
        float l = e;
        #pragma unroll
        for (int off = 32; off > 0; off >>= 1) l += __shfl_xor(l, off, 64);
        float w = e / l;   // lane jj holds weight for slot jj (jj < NJ)

        // dense weights row: 2048 f32 = 8 slots x (64 lanes x float4)
        float* row = Wts + ((size_t)h * SEQ + i) * SEQ;
        #pragma unroll
        for (int s = 0; s < 8; ++s) {
            float4 o;
            #pragma unroll
            for (int t = 0; t < 4; ++t) {
                int c = s * 256 + lane * 4 + t;
                bool in = (c < nsink) || (c >= lo && c <= i);
                int jjc = in ? ((c < nsink) ? c : (nsink + c - lo)) : 0;
                float wv2 = __shfl(w, jjc, 64);
                o[t] = in ? wv2 : 0.f;
            }
            *(float4*)(row + s * 256 + lane * 4) = o;
        }

        // PV from LDS (V rows 52..103)
        float o0 = 0.f, o1 = 0.f;
        for (int jj = 0; jj < NJ; ++jj) {
            int vrow;
            if (jj < nsink) vrow = 100 + jj;
            else {
                int widx = lo + jj - nsink - w0;
                vrow = 52 + widx;
            }
            float pb = __shfl(w, jj, 64);
            unsigned int vv = *(const unsigned int*)&sm[vrow * SMLD + 2 * lane];
            o0 += pb * bf2f((ushort_t)(vv & 0xffff));
            o1 += pb * bf2f((ushort_t)(vv >> 16));
        }
        int r = h * 128 + (i >> 4);
        int c = (i & 15) * 128 + 2 * lane;
        ushort_t* Ar = Aout + (size_t)r * HIDD + c;
        Ar[0] = f2bf(o0);
        Ar[1] = f2bf(o1);
    }
}

extern "C" void kernel_launch(void* const* d_in, const int* in_sizes, int n_in,
                              void* d_out, int out_size, void* d_ws, size_t ws_size,
                              hipStream_t stream) {
    if (n_in < 7) return;
    const float* hid  = (const float*)d_in[0];
    const float* cosp = (const float*)d_in[1];
    const float* sinp = (const float*)d_in[2];
    const float* Wq   = (const float*)d_in[3];
    const float* Wk   = (const float*)d_in[4];
    const float* Wv   = (const float*)d_in[5];
    const float* Wo   = (const float*)d_in[6];

    float* out = (float*)d_out;                  // attn_output (f32)
    float* wts = out + (size_t)SEQ * HIDD;       // attn_weights (f32)

    // workspace layout (all bf16 elems)
    ushort_t* Hb    = (ushort_t*)d_ws;                    // 2048x2048
    ushort_t* Wqkvt = Hb    + (size_t)2048 * 2048;        // 3072x2048
    ushort_t* Wot   = Wqkvt + (size_t)3072 * 2048;        // 2048x2048
    ushort_t* X     = Wot   + (size_t)2048 * 2048;        // 2048x3072
    ushort_t* Am    = X     + (size_t)SEQ * XLD;          // 2048x2048
    ushort_t* Pqkv  = Am    + (size_t)SEQ * HIDD;         // 2 x 2048x3072
    ushort_t* Pout  = Pqkv  + 2 * (size_t)SEQ * XLD;      // 3 x 2048x2048
    size_t need = ((char*)(Pout + 3 * (size_t)SEQ * HIDD)) - (char*)d_ws;
    if (ws_size < need) return;

    dim3 blk(256);
    // all weight transposes + hidden convert in one launch
    transpose_all<<<dim3(112, 32), blk, 0, stream>>>(
        Wq, Wk, Wv, Wo, hid, Wqkvt, Wot, Hb);

    // fused QKV projection, split-K=2 (1024+1024) -> bf16 partials
    gemm_splitk<<<dim3(24, 16, 2), blk, 0, stream>>>(
        Hb, HIDD, Wqkvt, 2048, Pqkv, XLD, make_int4(1024, 1024, 0, 0));
    reduce_x<<<(RWAVES + VWAVES) / 4, blk, 0, stream>>>(
        Pqkv, X, cosp, sinp);

    // attention: one block per (h, 16 queries), K/V staged in LDS
    attn_kernel<<<SEQ * 16 / 16, blk, 0, stream>>>(X, wts, Am);

    // output projection, split-K=3 (704+704+640, all x64, full residency)
    gemm_splitk<<<dim3(16, 16, 3), blk, 0, stream>>>(
        Am, HIDD, Wot, 2048, Pout, HIDD, make_int4(704, 704, 640, 0));
    reduce_out3<<<(SEQ * HIDD) / (256 * 4), blk, 0, stream>>>(Pout, out);
}